// Round 2
// baseline (392.173 us; speedup 1.0000x reference)
//
#include <hip/hip_runtime.h>

#define B_ 4
#define S_ 2048
#define D_ 1024
#define M_ 2048
#define J_ 8
#define H_ 16
#define HD_ 64
#define BH_ 64

typedef __attribute__((ext_vector_type(8))) short short8;
typedef __attribute__((ext_vector_type(4))) float f32x4;

static __device__ __forceinline__ unsigned short f2bf(float x) {
  unsigned u = __float_as_uint(x);
  u = u + 0x7fffu + ((u >> 16) & 1u);
  return (unsigned short)(u >> 16);
}

// G[9][1024]: rows 0..7 = memory @ W_out, row 8 = b_out
__global__ __launch_bounds__(256) void k_mw(const float* __restrict__ memory,
                                            const float* __restrict__ W_out,
                                            const float* __restrict__ b_out,
                                            float* __restrict__ G) {
  int nc = blockIdx.x;  // 16 blocks, 64 cols each
  int t = threadIdx.x;
  int n = nc * 64 + (t & 63);
  int kp = t >> 6;  // 4 k-partitions of 512
  float acc[J_];
#pragma unroll
  for (int j = 0; j < J_; ++j) acc[j] = 0.f;
  for (int k = kp * 512; k < kp * 512 + 512; ++k) {
    float wv = W_out[(size_t)k * D_ + n];
#pragma unroll
    for (int j = 0; j < J_; ++j) acc[j] += memory[j * M_ + k] * wv;
  }
  __shared__ float part[4][J_][64];
#pragma unroll
  for (int j = 0; j < J_; ++j) part[kp][j][t & 63] = acc[j];
  __syncthreads();
  if (t < 64) {
    int nn = nc * 64 + t;
#pragma unroll
    for (int j = 0; j < J_; ++j)
      G[j * D_ + nn] = part[0][j][t] + part[1][j][t] + part[2][j][t] + part[3][j][t];
    G[8 * D_ + nn] = b_out[nn];
  }
}

// H_w[9][1024] = G @ W_w  (row 8 becomes b_out @ W_w)
__global__ __launch_bounds__(256) void k_mwq(const float* __restrict__ G,
                                             const float* __restrict__ Wq,
                                             const float* __restrict__ Wk,
                                             const float* __restrict__ Wv,
                                             float* __restrict__ Hq,
                                             float* __restrict__ Hk,
                                             float* __restrict__ Hv) {
  int wi = blockIdx.x >> 4;  // 0..2 weight select
  int nc = blockIdx.x & 15;
  const float* W = wi == 0 ? Wq : (wi == 1 ? Wk : Wv);
  float* Hh = wi == 0 ? Hq : (wi == 1 ? Hk : Hv);
  int t = threadIdx.x;
  int n = nc * 64 + (t & 63);
  int kp = t >> 6;  // 4 partitions of 256
  float acc[9];
#pragma unroll
  for (int j = 0; j < 9; ++j) acc[j] = 0.f;
  for (int k = kp * 256; k < kp * 256 + 256; ++k) {
    float wv = W[(size_t)k * D_ + n];
#pragma unroll
    for (int j = 0; j < 9; ++j) acc[j] += G[j * D_ + k] * wv;
  }
  __shared__ float part[4][9][64];
#pragma unroll
  for (int j = 0; j < 9; ++j) part[kp][j][t & 63] = acc[j];
  __syncthreads();
  if (t < 64) {
    int nn = nc * 64 + t;
#pragma unroll
    for (int j = 0; j < 9; ++j)
      Hh[j * D_ + nn] = part[0][j][t] + part[1][j][t] + part[2][j][t] + part[3][j][t];
  }
}

// WoT[n][k] = bf16(Wo[k][n])
__global__ __launch_bounds__(256) void k_wot(const float* __restrict__ Wo,
                                             unsigned short* __restrict__ WoT) {
  int kt = blockIdx.x, nt = blockIdx.y;
  int t = threadIdx.x;
  __shared__ float tl[64][65];
  int r = t >> 6, c = t & 63;
#pragma unroll
  for (int i = 0; i < 16; ++i) {
    int row = i * 4 + r;
    tl[row][c] = Wo[(size_t)(kt * 64 + row) * D_ + nt * 64 + c];
  }
  __syncthreads();
#pragma unroll
  for (int i = 0; i < 16; ++i) {
    int nrow = i * 4 + r;
    WoT[(size_t)(nt * 64 + nrow) * D_ + kt * 64 + c] = f2bf(tl[c][nrow]);
  }
}

// per-token: theta[:4] -> p -> scores -> softmax addr[8] -> q,k,v rows (bf16)
__global__ __launch_bounds__(256) void k_qkv(
    const float* __restrict__ query, const float* __restrict__ W_addr,
    const float* __restrict__ b_addr, const float* __restrict__ Hq,
    const float* __restrict__ Hk, const float* __restrict__ Hv,
    const float* __restrict__ bq, const float* __restrict__ bk,
    const float* __restrict__ bv, unsigned short* __restrict__ Qg,
    unsigned short* __restrict__ Kg, unsigned short* __restrict__ Vg) {
  int tk = blockIdx.x;  // 0..8191
  int b = tk >> 11, s = tk & (S_ - 1);
  int t = threadIdx.x;
  float4 qv = ((const float4*)(query + (size_t)tk * D_))[t];
  float tq0 = 0.f, tq1 = 0.f, tq2 = 0.f, tq3 = 0.f;
  float xs[4] = {qv.x, qv.y, qv.z, qv.w};
#pragma unroll
  for (int e = 0; e < 4; ++e) {
    const float* wr = W_addr + (size_t)(t * 4 + e) * 16;
    tq0 += xs[e] * wr[0];
    tq1 += xs[e] * wr[1];
    tq2 += xs[e] * wr[2];
    tq3 += xs[e] * wr[3];
  }
#pragma unroll
  for (int off = 32; off; off >>= 1) {
    tq0 += __shfl_down(tq0, off);
    tq1 += __shfl_down(tq1, off);
    tq2 += __shfl_down(tq2, off);
    tq3 += __shfl_down(tq3, off);
  }
  __shared__ float red[4][4];
  __shared__ float aw[8];
  int w = t >> 6, lane = t & 63;
  if (lane == 0) {
    red[w][0] = tq0; red[w][1] = tq1; red[w][2] = tq2; red[w][3] = tq3;
  }
  __syncthreads();
  if (t == 0) {
    float p[4];
#pragma unroll
    for (int q = 0; q < 4; ++q) {
      float th = red[0][q] + red[1][q] + red[2][q] + red[3][q] + b_addr[q];
      float sh = __sinf(th * 0.5f);
      p[q] = th > 0.f ? sh * sh : 0.f;
    }
    float sc[8];
    float mx = -1e30f;
#pragma unroll
    for (int j = 0; j < 8; ++j) {
      float v = 0.f;
#pragma unroll
      for (int q = 0; q < 4; ++q) v += ((j >> q) & 1) ? p[q] : 1.f - p[q];
      sc[j] = v;
      mx = fmaxf(mx, v);
    }
    float sum = 0.f;
#pragma unroll
    for (int j = 0; j < 8; ++j) {
      sc[j] = __expf(sc[j] - mx);
      sum += sc[j];
    }
    float inv = 1.f / sum;
#pragma unroll
    for (int j = 0; j < 8; ++j) aw[j] = sc[j] * inv;
  }
  __syncthreads();
  float a[8];
#pragma unroll
  for (int j = 0; j < 8; ++j) a[j] = aw[j];
  int n0 = t * 4;
  int h = n0 >> 6, d = n0 & 63;
  size_t obase = ((size_t)(b * H_ + h) * S_ + s) * HD_ + d;
  const float* Hs[3] = {Hq, Hk, Hv};
  const float* bs[3] = {bq, bk, bv};
  unsigned short* os[3] = {Qg, Kg, Vg};
#pragma unroll
  for (int wi = 0; wi < 3; ++wi) {
    const float* Hh = Hs[wi];
    float4 accv = *(const float4*)(Hh + 8 * D_ + n0);
    float4 bias = *(const float4*)(bs[wi] + n0);
    accv.x += bias.x; accv.y += bias.y; accv.z += bias.z; accv.w += bias.w;
#pragma unroll
    for (int j = 0; j < 8; ++j) {
      float4 hv = *(const float4*)(Hh + j * D_ + n0);
      accv.x += a[j] * hv.x;
      accv.y += a[j] * hv.y;
      accv.z += a[j] * hv.z;
      accv.w += a[j] * hv.w;
    }
    uint2 pk;
    pk.x = (unsigned)f2bf(accv.x) | ((unsigned)f2bf(accv.y) << 16);
    pk.y = (unsigned)f2bf(accv.z) | ((unsigned)f2bf(accv.w) << 16);
    *(uint2*)(os[wi] + obase) = pk;
  }
}

// V (bh,s,d) -> Vt (bh,d,s)   [64x64 tiles; 256 threads stage 2 rows each]
__global__ __launch_bounds__(256) void k_vt(const unsigned short* __restrict__ Vg,
                                            unsigned short* __restrict__ Vtg) {
  int st = blockIdx.x & 31, bh = blockIdx.x >> 5;
  int t = threadIdx.x;
  __shared__ unsigned short tl[64][65];
  int rr = t >> 3, c8 = t & 7;
#pragma unroll
  for (int p = 0; p < 2; ++p) {
    int s = p * 32 + rr;
    uint4 v = *(const uint4*)(Vg + ((size_t)bh * S_ + st * 64 + s) * HD_ + c8 * 8);
    const unsigned short* pv = (const unsigned short*)&v;
#pragma unroll
    for (int j = 0; j < 8; ++j) tl[s][c8 * 8 + j] = pv[j];
  }
  __syncthreads();
#pragma unroll
  for (int p = 0; p < 2; ++p) {
    int d = p * 32 + rr;
    unsigned short o[8];
#pragma unroll
    for (int j = 0; j < 8; ++j) o[j] = tl[c8 * 8 + j][d];
    *(uint4*)(Vtg + ((size_t)bh * HD_ + d) * S_ + st * 64 + c8 * 8) = *(const uint4*)o;
  }
}

// flash attention: 4 waves x 16 q-rows, KVBLK=64, 16x16x32 bf16 MFMA
__global__ __launch_bounds__(256) void k_attn(const unsigned short* __restrict__ Qg,
                                              const unsigned short* __restrict__ Kg,
                                              const unsigned short* __restrict__ Vtg,
                                              unsigned short* __restrict__ ctxg) {
  int qt = blockIdx.x;  // 32 q-tiles
  int bh = blockIdx.y;  // 64
  int t = threadIdx.x;
  int w = t >> 6, l = t & 63;
  int l15 = l & 15, l4 = l >> 4;

  __shared__ __align__(16) unsigned short sK[64 * 64];
  __shared__ __align__(16) unsigned short sV[64 * 64];
  __shared__ __align__(16) unsigned short sP[4][16 * 64];

  int qrow = qt * 64 + w * 16 + l15;
  const unsigned short* qp = Qg + ((size_t)bh * S_ + qrow) * HD_ + l4 * 8;
  short8 aq0 = *(const short8*)(qp);
  short8 aq1 = *(const short8*)(qp + 32);

  f32x4 acc[4];
  float m[4], ls[4];
#pragma unroll
  for (int c = 0; c < 4; ++c) acc[c] = (f32x4){0.f, 0.f, 0.f, 0.f};
#pragma unroll
  for (int r = 0; r < 4; ++r) { m[r] = -1e30f; ls[r] = 0.f; }

  int srow = t >> 3, sc8 = t & 7;  // srow 0..31: stage 2 rows each (p*32+srow)
  const unsigned short* kgbase = Kg + (size_t)bh * S_ * HD_;
  const unsigned short* vtbase = Vtg + (size_t)bh * HD_ * S_;

  for (int kv0 = 0; kv0 < S_; kv0 += 64) {
    __syncthreads();
#pragma unroll
    for (int p = 0; p < 2; ++p) {
      int row = p * 32 + srow;
      int di = row * 64 + ((sc8 * 8) ^ ((row & 7) << 3));
      *(uint4*)(sK + di) =
          *(const uint4*)(kgbase + (size_t)(kv0 + row) * HD_ + sc8 * 8);
      *(uint4*)(sV + di) =
          *(const uint4*)(vtbase + (size_t)row * S_ + kv0 + sc8 * 8);
    }
    __syncthreads();

    f32x4 sv[4];
#pragma unroll
    for (int c = 0; c < 4; ++c) {
      int row = c * 16 + l15;
      int sw = (row & 7) << 3;
      short8 b0 = *(const short8*)(sK + row * 64 + ((l4 * 8) ^ sw));
      short8 b1 = *(const short8*)(sK + row * 64 + ((32 + l4 * 8) ^ sw));
      f32x4 z = (f32x4){0.f, 0.f, 0.f, 0.f};
      z = __builtin_amdgcn_mfma_f32_16x16x32_bf16(aq0, b0, z, 0, 0, 0);
      z = __builtin_amdgcn_mfma_f32_16x16x32_bf16(aq1, b1, z, 0, 0, 0);
      sv[c] = z;
    }
#pragma unroll
    for (int r = 0; r < 4; ++r) {
      float v0 = sv[0][r] * 0.125f, v1 = sv[1][r] * 0.125f;
      float v2 = sv[2][r] * 0.125f, v3 = sv[3][r] * 0.125f;
      float mx = fmaxf(fmaxf(v0, v1), fmaxf(v2, v3));
      mx = fmaxf(mx, __shfl_xor(mx, 1, 16));
      mx = fmaxf(mx, __shfl_xor(mx, 2, 16));
      mx = fmaxf(mx, __shfl_xor(mx, 4, 16));
      mx = fmaxf(mx, __shfl_xor(mx, 8, 16));
      float mn = fmaxf(m[r], mx);
      float scale = __expf(m[r] - mn);
      m[r] = mn;
      float p0 = __expf(v0 - mn), p1 = __expf(v1 - mn);
      float p2 = __expf(v2 - mn), p3 = __expf(v3 - mn);
      sv[0][r] = p0; sv[1][r] = p1; sv[2][r] = p2; sv[3][r] = p3;
      float sum = p0 + p1 + p2 + p3;
      sum += __shfl_xor(sum, 1, 16);
      sum += __shfl_xor(sum, 2, 16);
      sum += __shfl_xor(sum, 4, 16);
      sum += __shfl_xor(sum, 8, 16);
      ls[r] = ls[r] * scale + sum;
#pragma unroll
      for (int c = 0; c < 4; ++c) acc[c][r] *= scale;
    }
    unsigned short* pw = sP[w];
#pragma unroll
    for (int r = 0; r < 4; ++r) {
      int row = l4 * 4 + r;
      int sw = (row & 7) << 3;
#pragma unroll
      for (int c = 0; c < 4; ++c)
        pw[row * 64 + ((c * 16 + l15) ^ sw)] = f2bf(sv[c][r]);
    }
    int swp = (l15 & 7) << 3;
    short8 ap0 = *(const short8*)(pw + l15 * 64 + ((l4 * 8) ^ swp));
    short8 ap1 = *(const short8*)(pw + l15 * 64 + ((32 + l4 * 8) ^ swp));
#pragma unroll
    for (int c = 0; c < 4; ++c) {
      int row = c * 16 + l15;
      int sw = (row & 7) << 3;
      short8 b0 = *(const short8*)(sV + row * 64 + ((l4 * 8) ^ sw));
      short8 b1 = *(const short8*)(sV + row * 64 + ((32 + l4 * 8) ^ sw));
      acc[c] = __builtin_amdgcn_mfma_f32_16x16x32_bf16(ap0, b0, acc[c], 0, 0, 0);
      acc[c] = __builtin_amdgcn_mfma_f32_16x16x32_bf16(ap1, b1, acc[c], 0, 0, 0);
    }
  }
  int b = bh >> 4, h = bh & 15;
#pragma unroll
  for (int r = 0; r < 4; ++r) {
    float inv = 1.f / ls[r];
    int s = qt * 64 + w * 16 + l4 * 4 + r;
    size_t base = (size_t)(b * S_ + s) * D_ + h * HD_;
#pragma unroll
    for (int c = 0; c < 4; ++c)
      ctxg[base + c * 16 + l15] = f2bf(acc[c][r] * inv);
  }
}

// out[8192,1024] = ctx @ Wo + bo  (A row-major bf16, B as WoT n-major bf16)
__global__ __launch_bounds__(256) void k_out(const unsigned short* __restrict__ Ag,
                                             const unsigned short* __restrict__ Btg,
                                             const float* __restrict__ bo,
                                             float* __restrict__ out) {
  int mt = blockIdx.x;  // 64
  int nt = blockIdx.y;  // 8
  int t = threadIdx.x;
  int w = t >> 6, l = t & 63;
  int l15 = l & 15, l4 = l >> 4;
  int wr = w >> 1, wc = w & 1;
  __shared__ __align__(16) unsigned short sA[128 * 64];
  __shared__ __align__(16) unsigned short sB[128 * 64];
  f32x4 acc[4][4];
#pragma unroll
  for (int mm = 0; mm < 4; ++mm)
#pragma unroll
    for (int nn = 0; nn < 4; ++nn) acc[mm][nn] = (f32x4){0.f, 0.f, 0.f, 0.f};
  int srow = t >> 3, sc8 = t & 7;
  for (int kt = 0; kt < 16; ++kt) {
    int k0 = kt * 64;
    __syncthreads();
#pragma unroll
    for (int p = 0; p < 4; ++p) {
      int row = p * 32 + srow;
      int di = row * 64 + ((sc8 * 8) ^ ((row & 7) << 3));
      *(uint4*)(sA + di) =
          *(const uint4*)(Ag + (size_t)(mt * 128 + row) * D_ + k0 + sc8 * 8);
      *(uint4*)(sB + di) =
          *(const uint4*)(Btg + (size_t)(nt * 128 + row) * D_ + k0 + sc8 * 8);
    }
    __syncthreads();
    short8 a[4][2];
#pragma unroll
    for (int mm = 0; mm < 4; ++mm) {
      int row = wr * 64 + mm * 16 + l15;
      int sw = (row & 7) << 3;
      a[mm][0] = *(const short8*)(sA + row * 64 + ((l4 * 8) ^ sw));
      a[mm][1] = *(const short8*)(sA + row * 64 + ((32 + l4 * 8) ^ sw));
    }
#pragma unroll
    for (int nn = 0; nn < 4; ++nn) {
      int row = wc * 64 + nn * 16 + l15;
      int sw = (row & 7) << 3;
      short8 b0 = *(const short8*)(sB + row * 64 + ((l4 * 8) ^ sw));
      short8 b1 = *(const short8*)(sB + row * 64 + ((32 + l4 * 8) ^ sw));
#pragma unroll
      for (int mm = 0; mm < 4; ++mm) {
        acc[mm][nn] = __builtin_amdgcn_mfma_f32_16x16x32_bf16(a[mm][0], b0, acc[mm][nn], 0, 0, 0);
        acc[mm][nn] = __builtin_amdgcn_mfma_f32_16x16x32_bf16(a[mm][1], b1, acc[mm][nn], 0, 0, 0);
      }
    }
  }
#pragma unroll
  for (int mm = 0; mm < 4; ++mm) {
#pragma unroll
    for (int r = 0; r < 4; ++r) {
      int mrow = mt * 128 + wr * 64 + mm * 16 + l4 * 4 + r;
      float* orow = out + (size_t)mrow * D_ + nt * 128 + wc * 64;
#pragma unroll
      for (int nn = 0; nn < 4; ++nn) {
        int n = nn * 16 + l15;
        orow[n] = acc[mm][nn][r] + bo[nt * 128 + wc * 64 + n];
      }
    }
  }
}

extern "C" void kernel_launch(void* const* d_in, const int* in_sizes, int n_in,
                              void* d_out, int out_size, void* d_ws, size_t ws_size,
                              hipStream_t stream) {
  const float* query = (const float*)d_in[0];
  const float* W_addr = (const float*)d_in[1];
  const float* b_addr = (const float*)d_in[2];
  const float* memory = (const float*)d_in[3];
  const float* W_out = (const float*)d_in[4];
  const float* b_out = (const float*)d_in[5];
  const float* Wq = (const float*)d_in[6];
  const float* bq = (const float*)d_in[7];
  const float* Wk = (const float*)d_in[8];
  const float* bk = (const float*)d_in[9];
  const float* Wv = (const float*)d_in[10];
  const float* bv = (const float*)d_in[11];
  const float* Wo = (const float*)d_in[12];
  const float* bo = (const float*)d_in[13];
  float* out = (float*)d_out;

  char* ws = (char*)d_ws;
  size_t off = 0;
  auto alloc = [&](size_t bytes) {
    char* p = ws + off;
    off = (off + bytes + 255) & ~(size_t)255;
    return p;
  };
  float* G = (float*)alloc(9 * D_ * sizeof(float));
  float* HqA = (float*)alloc(9 * D_ * sizeof(float));
  float* HkA = (float*)alloc(9 * D_ * sizeof(float));
  float* HvA = (float*)alloc(9 * D_ * sizeof(float));
  unsigned short* WoT = (unsigned short*)alloc((size_t)D_ * D_ * 2);
  unsigned short* Vg = (unsigned short*)alloc((size_t)BH_ * S_ * HD_ * 2);
  unsigned short* Vtg = (unsigned short*)alloc((size_t)BH_ * S_ * HD_ * 2);
  // Q and K live in d_out (exactly 2 x 16.8MB bf16); k_out overwrites it last.
  unsigned short* Qg = (unsigned short*)d_out;
  unsigned short* Kg = Qg + (size_t)BH_ * S_ * HD_;
  // ctx reuses Vg after k_vt is done with it.
  unsigned short* ctx = Vg;

  k_mw<<<16, 256, 0, stream>>>(memory, W_out, b_out, G);
  k_mwq<<<48, 256, 0, stream>>>(G, Wq, Wk, Wv, HqA, HkA, HvA);
  k_wot<<<dim3(16, 16), 256, 0, stream>>>(Wo, WoT);
  k_qkv<<<B_ * S_, 256, 0, stream>>>(query, W_addr, b_addr, HqA, HkA, HvA, bq, bk,
                                     bv, Qg, Kg, Vg);
  k_vt<<<BH_ * 32, 256, 0, stream>>>(Vg, Vtg);
  k_attn<<<dim3(32, BH_), 256, 0, stream>>>(Qg, Kg, Vtg, ctx);
  k_out<<<dim3(64, 8), 256, 0, stream>>>(ctx, WoT, bo, out);
}

// Round 3
// 334.995 us; speedup vs baseline: 1.1707x; 1.1707x over previous
//
#include <hip/hip_runtime.h>

#define B_ 4
#define S_ 2048
#define D_ 1024
#define M_ 2048
#define J_ 8
#define H_ 16
#define HD_ 64
#define BH_ 64

typedef __attribute__((ext_vector_type(8))) short short8;
typedef __attribute__((ext_vector_type(4))) float f32x4;
typedef __attribute__((ext_vector_type(16))) float f32x16;

static __device__ __forceinline__ unsigned short f2bf(float x) {
  unsigned u = __float_as_uint(x);
  u = u + 0x7fffu + ((u >> 16) & 1u);
  return (unsigned short)(u >> 16);
}

static __device__ __forceinline__ unsigned cvtpk(float lo, float hi) {
  unsigned r;
  asm("v_cvt_pk_bf16_f32 %0, %1, %2" : "=v"(r) : "v"(lo), "v"(hi));
  return r;
}

// G[9][1024]: rows 0..7 = memory @ W_out, row 8 = b_out
__global__ __launch_bounds__(256) void k_mw(const float* __restrict__ memory,
                                            const float* __restrict__ W_out,
                                            const float* __restrict__ b_out,
                                            float* __restrict__ G) {
  int nc = blockIdx.x;
  int t = threadIdx.x;
  int n = nc * 64 + (t & 63);
  int kp = t >> 6;
  float acc[J_];
#pragma unroll
  for (int j = 0; j < J_; ++j) acc[j] = 0.f;
  for (int k = kp * 512; k < kp * 512 + 512; ++k) {
    float wv = W_out[(size_t)k * D_ + n];
#pragma unroll
    for (int j = 0; j < J_; ++j) acc[j] += memory[j * M_ + k] * wv;
  }
  __shared__ float part[4][J_][64];
#pragma unroll
  for (int j = 0; j < J_; ++j) part[kp][j][t & 63] = acc[j];
  __syncthreads();
  if (t < 64) {
    int nn = nc * 64 + t;
#pragma unroll
    for (int j = 0; j < J_; ++j)
      G[j * D_ + nn] = part[0][j][t] + part[1][j][t] + part[2][j][t] + part[3][j][t];
    G[8 * D_ + nn] = b_out[nn];
  }
}

// H_w[9][1024] = G @ W_w
__global__ __launch_bounds__(256) void k_mwq(const float* __restrict__ G,
                                             const float* __restrict__ Wq,
                                             const float* __restrict__ Wk,
                                             const float* __restrict__ Wv,
                                             float* __restrict__ Hq,
                                             float* __restrict__ Hk,
                                             float* __restrict__ Hv) {
  int wi = blockIdx.x >> 4;
  int nc = blockIdx.x & 15;
  const float* W = wi == 0 ? Wq : (wi == 1 ? Wk : Wv);
  float* Hh = wi == 0 ? Hq : (wi == 1 ? Hk : Hv);
  int t = threadIdx.x;
  int n = nc * 64 + (t & 63);
  int kp = t >> 6;
  float acc[9];
#pragma unroll
  for (int j = 0; j < 9; ++j) acc[j] = 0.f;
  for (int k = kp * 256; k < kp * 256 + 256; ++k) {
    float wv = W[(size_t)k * D_ + n];
#pragma unroll
    for (int j = 0; j < 9; ++j) acc[j] += G[j * D_ + k] * wv;
  }
  __shared__ float part[4][9][64];
#pragma unroll
  for (int j = 0; j < 9; ++j) part[kp][j][t & 63] = acc[j];
  __syncthreads();
  if (t < 64) {
    int nn = nc * 64 + t;
#pragma unroll
    for (int j = 0; j < 9; ++j)
      Hh[j * D_ + nn] = part[0][j][t] + part[1][j][t] + part[2][j][t] + part[3][j][t];
  }
}

// WoT[n][k] = bf16(Wo[k][n])
__global__ __launch_bounds__(256) void k_wot(const float* __restrict__ Wo,
                                             unsigned short* __restrict__ WoT) {
  int kt = blockIdx.x, nt = blockIdx.y;
  int t = threadIdx.x;
  __shared__ float tl[64][65];
  int r = t >> 6, c = t & 63;
#pragma unroll
  for (int i = 0; i < 16; ++i) {
    int row = i * 4 + r;
    tl[row][c] = Wo[(size_t)(kt * 64 + row) * D_ + nt * 64 + c];
  }
  __syncthreads();
#pragma unroll
  for (int i = 0; i < 16; ++i) {
    int nrow = i * 4 + r;
    WoT[(size_t)(nt * 64 + nrow) * D_ + kt * 64 + c] = f2bf(tl[c][nrow]);
  }
}

// wave-per-token: theta[:4] -> p -> scores -> softmax addr[8] -> q,k,v rows
__global__ __launch_bounds__(256) void k_qkv(
    const float* __restrict__ query, const float* __restrict__ W_addr,
    const float* __restrict__ b_addr, const float* __restrict__ Hq,
    const float* __restrict__ Hk, const float* __restrict__ Hv,
    const float* __restrict__ bq, const float* __restrict__ bk,
    const float* __restrict__ bv, unsigned short* __restrict__ Qg,
    unsigned short* __restrict__ Kg, unsigned short* __restrict__ Vg) {
  int w = threadIdx.x >> 6, l = threadIdx.x & 63;
  int tk = blockIdx.x * 4 + w;
  int b = tk >> 11, s = tk & (S_ - 1);
  const float* qrow = query + (size_t)tk * D_;
  float th0 = 0.f, th1 = 0.f, th2 = 0.f, th3 = 0.f;
#pragma unroll
  for (int e = 0; e < 4; ++e) {
    float4 qv = *(const float4*)(qrow + l * 16 + e * 4);
    float xs[4] = {qv.x, qv.y, qv.z, qv.w};
#pragma unroll
    for (int kk = 0; kk < 4; ++kk) {
      float4 wr = *(const float4*)(W_addr + (size_t)(l * 16 + e * 4 + kk) * 16);
      th0 += xs[kk] * wr.x;
      th1 += xs[kk] * wr.y;
      th2 += xs[kk] * wr.z;
      th3 += xs[kk] * wr.w;
    }
  }
#pragma unroll
  for (int off = 32; off; off >>= 1) {
    th0 += __shfl_xor(th0, off);
    th1 += __shfl_xor(th1, off);
    th2 += __shfl_xor(th2, off);
    th3 += __shfl_xor(th3, off);
  }
  float thv[4] = {th0 + b_addr[0], th1 + b_addr[1], th2 + b_addr[2],
                  th3 + b_addr[3]};
  float p[4];
#pragma unroll
  for (int q = 0; q < 4; ++q) {
    float sh = __sinf(thv[q] * 0.5f);
    p[q] = thv[q] > 0.f ? sh * sh : 0.f;
  }
  float sc[8];
  float mx = -1e30f;
#pragma unroll
  for (int j = 0; j < 8; ++j) {
    float v = 0.f;
#pragma unroll
    for (int q = 0; q < 4; ++q) v += ((j >> q) & 1) ? p[q] : 1.f - p[q];
    sc[j] = v;
    mx = fmaxf(mx, v);
  }
  float sum = 0.f;
#pragma unroll
  for (int j = 0; j < 8; ++j) {
    sc[j] = __expf(sc[j] - mx);
    sum += sc[j];
  }
  float inv = 1.f / sum;
  float a[8];
#pragma unroll
  for (int j = 0; j < 8; ++j) a[j] = sc[j] * inv;

  const float* Hs[3] = {Hq, Hk, Hv};
  const float* bs[3] = {bq, bk, bv};
  unsigned short* os[3] = {Qg, Kg, Vg};
#pragma unroll
  for (int k = 0; k < 4; ++k) {
    int n0 = k * 256 + l * 4;
    int hh = n0 >> 6, d = n0 & 63;
    size_t obase = ((size_t)(b * H_ + hh) * S_ + s) * HD_ + d;
#pragma unroll
    for (int wi = 0; wi < 3; ++wi) {
      const float* Hh = Hs[wi];
      float4 accv = *(const float4*)(Hh + 8 * D_ + n0);
      float4 bias = *(const float4*)(bs[wi] + n0);
      accv.x += bias.x; accv.y += bias.y; accv.z += bias.z; accv.w += bias.w;
#pragma unroll
      for (int j = 0; j < 8; ++j) {
        float4 hv = *(const float4*)(Hh + j * D_ + n0);
        accv.x += a[j] * hv.x;
        accv.y += a[j] * hv.y;
        accv.z += a[j] * hv.z;
        accv.w += a[j] * hv.w;
      }
      uint2 pk;
      pk.x = (unsigned)f2bf(accv.x) | ((unsigned)f2bf(accv.y) << 16);
      pk.y = (unsigned)f2bf(accv.z) | ((unsigned)f2bf(accv.w) << 16);
      *(uint2*)(os[wi] + obase) = pk;
    }
  }
}

// V (bh,s,d) -> Vt (bh,d,s)
__global__ __launch_bounds__(256) void k_vt(const unsigned short* __restrict__ Vg,
                                            unsigned short* __restrict__ Vtg) {
  int st = blockIdx.x & 31, bh = blockIdx.x >> 5;
  int t = threadIdx.x;
  __shared__ unsigned short tl[64][65];
  int rr = t >> 3, c8 = t & 7;
#pragma unroll
  for (int p = 0; p < 2; ++p) {
    int s = p * 32 + rr;
    uint4 v = *(const uint4*)(Vg + ((size_t)bh * S_ + st * 64 + s) * HD_ + c8 * 8);
    const unsigned short* pv = (const unsigned short*)&v;
#pragma unroll
    for (int j = 0; j < 8; ++j) tl[s][c8 * 8 + j] = pv[j];
  }
  __syncthreads();
#pragma unroll
  for (int p = 0; p < 2; ++p) {
    int d = p * 32 + rr;
    unsigned short o[8];
#pragma unroll
    for (int j = 0; j < 8; ++j) o[j] = tl[c8 * 8 + j][d];
    *(uint4*)(Vtg + ((size_t)bh * HD_ + d) * S_ + st * 64 + c8 * 8) = *(const uint4*)o;
  }
}

// flash attention, swapped-operand 32x32: 4 waves x 32 q-rows, KVBLK=64.
// S' = mfma(K, Q^T): lane owns q = l&31; kv local index = (r&3)+8*(r>>2)+4*(l>>5).
// Softmax fully in-lane + one shfl_xor(32). PV: O' = mfma(Vt, P) keeps state local.
__global__ __launch_bounds__(256) void k_attn(const unsigned short* __restrict__ Qg,
                                              const unsigned short* __restrict__ Kg,
                                              const unsigned short* __restrict__ Vtg,
                                              unsigned short* __restrict__ ctxg) {
  int qt = blockIdx.x;   // 16
  int bh = blockIdx.y;   // 64
  int t = threadIdx.x;
  int w = t >> 6, l = t & 63;
  int q31 = l & 31, h = l >> 5;

  __shared__ __align__(16) unsigned short lds[8192];  // sK | sVt ; reused as sO
  unsigned short* sK = lds;
  unsigned short* sVt = lds + 4096;

  int q0 = qt * 128 + w * 32;
  const unsigned short* qp = Qg + ((size_t)bh * S_ + q0 + q31) * HD_;
  short8 qf0 = *(const short8*)(qp + 0 + h * 8);
  short8 qf1 = *(const short8*)(qp + 16 + h * 8);
  short8 qf2 = *(const short8*)(qp + 32 + h * 8);
  short8 qf3 = *(const short8*)(qp + 48 + h * 8);

  f32x16 accO0 = {}, accO1 = {};
  float m = -1e30f, lsum = 0.f;

  int srow = t >> 3, sc8 = t & 7;
  const unsigned short* kgb = Kg + (size_t)bh * S_ * HD_;
  const unsigned short* vtb = Vtg + (size_t)bh * HD_ * S_;

  for (int kv0 = 0; kv0 < S_; kv0 += 64) {
    __syncthreads();
#pragma unroll
    for (int p = 0; p < 2; ++p) {
      int row = p * 32 + srow;
      int di = row * 64 + ((sc8 * 8) ^ ((row & 7) << 3));
      *(uint4*)(sK + di) = *(const uint4*)(kgb + (size_t)(kv0 + row) * HD_ + sc8 * 8);
      *(uint4*)(sVt + di) = *(const uint4*)(vtb + (size_t)row * S_ + kv0 + sc8 * 8);
    }
    __syncthreads();

    // QK^T: accS[c] = S'[kv = c*32 + rows][q = l&31]
    f32x16 accS0 = {}, accS1 = {};
#pragma unroll
    for (int ds = 0; ds < 4; ++ds) {
      short8 qq = ds == 0 ? qf0 : ds == 1 ? qf1 : ds == 2 ? qf2 : qf3;
      {
        int row = q31;
        int g = (ds * 2 + h) ^ (row & 7);
        short8 kf = *(const short8*)(sK + row * 64 + g * 8);
        accS0 = __builtin_amdgcn_mfma_f32_32x32x16_bf16(kf, qq, accS0, 0, 0, 0);
      }
      {
        int row = 32 + q31;
        int g = (ds * 2 + h) ^ (row & 7);
        short8 kf = *(const short8*)(sK + row * 64 + g * 8);
        accS1 = __builtin_amdgcn_mfma_f32_32x32x16_bf16(kf, qq, accS1, 0, 0, 0);
      }
    }

    // in-lane softmax (q = l&31), cross-half via shfl_xor(32)
    float mxv = accS0[0];
#pragma unroll
    for (int r = 1; r < 16; ++r) mxv = fmaxf(mxv, accS0[r]);
#pragma unroll
    for (int r = 0; r < 16; ++r) mxv = fmaxf(mxv, accS1[r]);
    mxv = fmaxf(mxv, __shfl_xor(mxv, 32));
    float pm = mxv * 0.125f;
    if (__ballot(pm > m + 8.f)) {  // defer-max (T13)
      float mn = fmaxf(m, pm);
      float scl = __builtin_exp2f((m - mn) * 1.44269504f);
#pragma unroll
      for (int r = 0; r < 16; ++r) {
        accO0[r] *= scl;
        accO1[r] *= scl;
      }
      lsum *= scl;
      m = mn;
    }
    const float K1 = 0.125f * 1.44269504f;
    float m2 = m * 1.44269504f;
    float ts = 0.f;
#pragma unroll
    for (int r = 0; r < 16; ++r) {
      float p0 = __builtin_exp2f(accS0[r] * K1 - m2);
      float p1 = __builtin_exp2f(accS1[r] * K1 - m2);
      accS0[r] = p0;
      accS1[r] = p1;
      ts += p0 + p1;
    }
    ts += __shfl_xor(ts, 32);
    lsum += ts;

    // P -> bf16 B-fragments (T12, shfl+select half-exchange)
    short8 pb[4];
#pragma unroll
    for (int ks = 0; ks < 4; ++ks) {
      const int r0 = 8 * (ks & 1);
      float v0, v1, v2, v3, v4, v5, v6, v7;
      if (ks < 2) {
        v0 = accS0[r0 + 0]; v1 = accS0[r0 + 1]; v2 = accS0[r0 + 2]; v3 = accS0[r0 + 3];
        v4 = accS0[r0 + 4]; v5 = accS0[r0 + 5]; v6 = accS0[r0 + 6]; v7 = accS0[r0 + 7];
      } else {
        v0 = accS1[r0 + 0]; v1 = accS1[r0 + 1]; v2 = accS1[r0 + 2]; v3 = accS1[r0 + 3];
        v4 = accS1[r0 + 4]; v5 = accS1[r0 + 5]; v6 = accS1[r0 + 6]; v7 = accS1[r0 + 7];
      }
      unsigned X0 = cvtpk(v0, v1), X1 = cvtpk(v2, v3);
      unsigned Y0 = cvtpk(v4, v5), Y1 = cvtpk(v6, v7);
      unsigned tX0 = __shfl_xor(X0, 32), tX1 = __shfl_xor(X1, 32);
      unsigned tY0 = __shfl_xor(Y0, 32), tY1 = __shfl_xor(Y1, 32);
      union { unsigned u[4]; short8 s8; } uu;
      uu.u[0] = h ? tY0 : X0;
      uu.u[1] = h ? tY1 : X1;
      uu.u[2] = h ? Y0 : tX0;
      uu.u[3] = h ? Y1 : tX1;
      pb[ks] = uu.s8;
    }

    // PV: accO[n] (rows = d, cols = q)
    {
      int row = q31;
      int rs = row & 7;
#pragma unroll
      for (int ks = 0; ks < 4; ++ks) {
        int g = (ks * 2 + h) ^ rs;
        short8 vf = *(const short8*)(sVt + row * 64 + g * 8);
        accO0 = __builtin_amdgcn_mfma_f32_32x32x16_bf16(vf, pb[ks], accO0, 0, 0, 0);
      }
    }
    {
      int row = 32 + q31;
      int rs = row & 7;
#pragma unroll
      for (int ks = 0; ks < 4; ++ks) {
        int g = (ks * 2 + h) ^ rs;
        short8 vf = *(const short8*)(sVt + row * 64 + g * 8);
        accO1 = __builtin_amdgcn_mfma_f32_32x32x16_bf16(vf, pb[ks], accO1, 0, 0, 0);
      }
    }
  }

  // O out: normalize (lane-local lsum), bounce through LDS for coalesced stores
  __syncthreads();
  float inv = 1.f / lsum;
  unsigned short* sO = lds + w * 2048;  // [32 q][64 d], granule-8 XOR swizzle
#pragma unroll
  for (int r = 0; r < 16; ++r) {
    int dl = (r & 3) + 8 * (r >> 2) + 4 * h;
    int swz = (q31 & 7) << 3;
    sO[q31 * 64 + (dl ^ swz)] = f2bf(accO0[r] * inv);
    sO[q31 * 64 + ((32 + dl) ^ swz)] = f2bf(accO1[r] * inv);
  }
  __syncthreads();
  int b = bh >> 4, head = bh & 15;
  int rr = l & 31, hh = l >> 5;
  unsigned short* orow = ctxg + ((size_t)(b * S_ + q0 + rr)) * D_ + head * HD_;
#pragma unroll
  for (int j = 0; j < 4; ++j) {
    int g = hh * 4 + j;
    uint4 vv = *(const uint4*)(sO + rr * 64 + ((g ^ (rr & 7)) * 8));
    *(uint4*)(orow + g * 8) = vv;
  }
}

// out[8192,1024] = ctx @ Wo + bo
__global__ __launch_bounds__(256) void k_out(const unsigned short* __restrict__ Ag,
                                             const unsigned short* __restrict__ Btg,
                                             const float* __restrict__ bo,
                                             float* __restrict__ out) {
  int mt = blockIdx.x;
  int nt = blockIdx.y;
  int t = threadIdx.x;
  int w = t >> 6, l = t & 63;
  int l15 = l & 15, l4 = l >> 4;
  int wr = w >> 1, wc = w & 1;
  __shared__ __align__(16) unsigned short sA[128 * 64];
  __shared__ __align__(16) unsigned short sB[128 * 64];
  f32x4 acc[4][4];
#pragma unroll
  for (int mm = 0; mm < 4; ++mm)
#pragma unroll
    for (int nn = 0; nn < 4; ++nn) acc[mm][nn] = (f32x4){0.f, 0.f, 0.f, 0.f};
  int srow = t >> 3, sc8 = t & 7;
  for (int kt = 0; kt < 16; ++kt) {
    int k0 = kt * 64;
    __syncthreads();
#pragma unroll
    for (int p = 0; p < 4; ++p) {
      int row = p * 32 + srow;
      int di = row * 64 + ((sc8 * 8) ^ ((row & 7) << 3));
      *(uint4*)(sA + di) =
          *(const uint4*)(Ag + (size_t)(mt * 128 + row) * D_ + k0 + sc8 * 8);
      *(uint4*)(sB + di) =
          *(const uint4*)(Btg + (size_t)(nt * 128 + row) * D_ + k0 + sc8 * 8);
    }
    __syncthreads();
    short8 a[4][2];
#pragma unroll
    for (int mm = 0; mm < 4; ++mm) {
      int row = wr * 64 + mm * 16 + l15;
      int sw = (row & 7) << 3;
      a[mm][0] = *(const short8*)(sA + row * 64 + ((l4 * 8) ^ sw));
      a[mm][1] = *(const short8*)(sA + row * 64 + ((32 + l4 * 8) ^ sw));
    }
#pragma unroll
    for (int nn = 0; nn < 4; ++nn) {
      int row = wc * 64 + nn * 16 + l15;
      int sw = (row & 7) << 3;
      short8 b0 = *(const short8*)(sB + row * 64 + ((l4 * 8) ^ sw));
      short8 b1 = *(const short8*)(sB + row * 64 + ((32 + l4 * 8) ^ sw));
#pragma unroll
      for (int mm = 0; mm < 4; ++mm) {
        acc[mm][nn] = __builtin_amdgcn_mfma_f32_16x16x32_bf16(a[mm][0], b0, acc[mm][nn], 0, 0, 0);
        acc[mm][nn] = __builtin_amdgcn_mfma_f32_16x16x32_bf16(a[mm][1], b1, acc[mm][nn], 0, 0, 0);
      }
    }
  }
#pragma unroll
  for (int mm = 0; mm < 4; ++mm) {
#pragma unroll
    for (int r = 0; r < 4; ++r) {
      int mrow = mt * 128 + wr * 64 + mm * 16 + l4 * 4 + r;
      float* orow = out + (size_t)mrow * D_ + nt * 128 + wc * 64;
#pragma unroll
      for (int nn = 0; nn < 4; ++nn) {
        int n = nn * 16 + l15;
        orow[n] = acc[mm][nn][r] + bo[nt * 128 + wc * 64 + n];
      }
    }
  }
}

extern "C" void kernel_launch(void* const* d_in, const int* in_sizes, int n_in,
                              void* d_out, int out_size, void* d_ws, size_t ws_size,
                              hipStream_t stream) {
  const float* query = (const float*)d_in[0];
  const float* W_addr = (const float*)d_in[1];
  const float* b_addr = (const float*)d_in[2];
  const float* memory = (const float*)d_in[3];
  const float* W_out = (const float*)d_in[4];
  const float* b_out = (const float*)d_in[5];
  const float* Wq = (const float*)d_in[6];
  const float* bq = (const float*)d_in[7];
  const float* Wk = (const float*)d_in[8];
  const float* bk = (const float*)d_in[9];
  const float* Wv = (const float*)d_in[10];
  const float* bv = (const float*)d_in[11];
  const float* Wo = (const float*)d_in[12];
  const float* bo = (const float*)d_in[13];
  float* out = (float*)d_out;

  char* ws = (char*)d_ws;
  size_t off = 0;
  auto alloc = [&](size_t bytes) {
    char* p = ws + off;
    off = (off + bytes + 255) & ~(size_t)255;
    return p;
  };
  float* G = (float*)alloc(9 * D_ * sizeof(float));
  float* HqA = (float*)alloc(9 * D_ * sizeof(float));
  float* HkA = (float*)alloc(9 * D_ * sizeof(float));
  float* HvA = (float*)alloc(9 * D_ * sizeof(float));
  unsigned short* WoT = (unsigned short*)alloc((size_t)D_ * D_ * 2);
  unsigned short* Vg = (unsigned short*)alloc((size_t)BH_ * S_ * HD_ * 2);
  unsigned short* Vtg = (unsigned short*)alloc((size_t)BH_ * S_ * HD_ * 2);
  unsigned short* Qg = (unsigned short*)d_out;
  unsigned short* Kg = Qg + (size_t)BH_ * S_ * HD_;
  unsigned short* ctx = Vg;

  k_mw<<<16, 256, 0, stream>>>(memory, W_out, b_out, G);
  k_mwq<<<48, 256, 0, stream>>>(G, Wq, Wk, Wv, HqA, HkA, HvA);
  k_wot<<<dim3(16, 16), 256, 0, stream>>>(Wo, WoT);
  k_qkv<<<B_ * S_ / 4, 256, 0, stream>>>(query, W_addr, b_addr, HqA, HkA, HvA,
                                         bq, bk, bv, Qg, Kg, Vg);
  k_vt<<<BH_ * 32, 256, 0, stream>>>(Vg, Vtg);
  k_attn<<<dim3(16, BH_), 256, 0, stream>>>(Qg, Kg, Vtg, ctx);
  k_out<<<dim3(64, 8), 256, 0, stream>>>(ctx, WoT, bo, out);
}

// Round 4
// 247.662 us; speedup vs baseline: 1.5835x; 1.3526x over previous
//
#include <hip/hip_runtime.h>

#define B_ 4
#define S_ 2048
#define D_ 1024
#define M_ 2048
#define J_ 8
#define H_ 16
#define HD_ 64
#define BH_ 64

typedef __attribute__((ext_vector_type(8))) short short8;
typedef __attribute__((ext_vector_type(4))) float f32x4;
typedef __attribute__((ext_vector_type(16))) float f32x16;

static __device__ __forceinline__ unsigned short f2bf(float x) {
  unsigned u = __float_as_uint(x);
  u = u + 0x7fffu + ((u >> 16) & 1u);
  return (unsigned short)(u >> 16);
}

static __device__ __forceinline__ unsigned cvtpk(float lo, float hi) {
  unsigned r;
  asm("v_cvt_pk_bf16_f32 %0, %1, %2" : "=v"(r) : "v"(lo), "v"(hi));
  return r;
}

// ---- memory @ W_out, k-split partials: part[16][8][1024] ----
__global__ __launch_bounds__(256) void k_mw_part(const float* __restrict__ memory,
                                                 const float* __restrict__ W_out,
                                                 float* __restrict__ part) {
  int nc = blockIdx.x >> 4, ks = blockIdx.x & 15;
  int t = threadIdx.x;
  int n = nc * 64 + (t & 63);
  int sub = t >> 6;
  int k0 = ks * 128 + sub * 32;
  float acc[J_];
#pragma unroll
  for (int j = 0; j < J_; ++j) acc[j] = 0.f;
  for (int k = k0; k < k0 + 32; ++k) {
    float wv = W_out[(size_t)k * D_ + n];
#pragma unroll
    for (int j = 0; j < J_; ++j) acc[j] += memory[j * M_ + k] * wv;
  }
  __shared__ float p4[4][J_][64];
#pragma unroll
  for (int j = 0; j < J_; ++j) p4[sub][j][t & 63] = acc[j];
  __syncthreads();
  if (t < 64) {
#pragma unroll
    for (int j = 0; j < J_; ++j)
      part[((size_t)ks * J_ + j) * D_ + nc * 64 + t] =
          p4[0][j][t] + p4[1][j][t] + p4[2][j][t] + p4[3][j][t];
  }
}

// G[9][1024]: rows 0..7 reduce partials, row 8 = b_out
__global__ __launch_bounds__(256) void k_mw_red(const float* __restrict__ part,
                                                const float* __restrict__ b_out,
                                                float* __restrict__ G) {
  int id = blockIdx.x * 256 + threadIdx.x;  // 0..9215
  int j = id >> 10, n = id & 1023;
  if (j < 8) {
    float s = 0.f;
#pragma unroll
    for (int ks = 0; ks < 16; ++ks) s += part[((size_t)ks * J_ + j) * D_ + n];
    G[j * D_ + n] = s;
  } else {
    G[8 * D_ + n] = b_out[n];
  }
}

// G @ W_w, k-split partials: partq[3][4][9][1024]
__global__ __launch_bounds__(256) void k_mwq_part(const float* __restrict__ G,
                                                  const float* __restrict__ Wq,
                                                  const float* __restrict__ Wk,
                                                  const float* __restrict__ Wv,
                                                  float* __restrict__ partq) {
  int wi = blockIdx.x >> 6;
  int r = blockIdx.x & 63;
  int nc = r & 15, ks = r >> 4;
  const float* W = wi == 0 ? Wq : (wi == 1 ? Wk : Wv);
  int t = threadIdx.x;
  int n = nc * 64 + (t & 63);
  int sub = t >> 6;
  int k0 = ks * 256 + sub * 64;
  float acc[9];
#pragma unroll
  for (int j = 0; j < 9; ++j) acc[j] = 0.f;
  for (int k = k0; k < k0 + 64; ++k) {
    float wv = W[(size_t)k * D_ + n];
#pragma unroll
    for (int j = 0; j < 9; ++j) acc[j] += G[j * D_ + k] * wv;
  }
  __shared__ float p4[4][9][64];
#pragma unroll
  for (int j = 0; j < 9; ++j) p4[sub][j][t & 63] = acc[j];
  __syncthreads();
  if (t < 64) {
#pragma unroll
    for (int j = 0; j < 9; ++j)
      partq[(((size_t)wi * 4 + ks) * 9 + j) * D_ + nc * 64 + t] =
          p4[0][j][t] + p4[1][j][t] + p4[2][j][t] + p4[3][j][t];
  }
}

__global__ __launch_bounds__(256) void k_mwq_red(const float* __restrict__ partq,
                                                 float* __restrict__ Hq,
                                                 float* __restrict__ Hk,
                                                 float* __restrict__ Hv) {
  int id = blockIdx.x * 256 + threadIdx.x;  // 0..27647
  int wi = id / 9216;
  int rem = id - wi * 9216;
  int j = rem >> 10, n = rem & 1023;
  float s = 0.f;
#pragma unroll
  for (int ks = 0; ks < 4; ++ks)
    s += partq[(((size_t)wi * 4 + ks) * 9 + j) * D_ + n];
  float* Hh = wi == 0 ? Hq : (wi == 1 ? Hk : Hv);
  Hh[j * D_ + n] = s;
}

// WoT[n][k] = bf16(Wo[k][n])
__global__ __launch_bounds__(256) void k_wot(const float* __restrict__ Wo,
                                             unsigned short* __restrict__ WoT) {
  int kt = blockIdx.x, nt = blockIdx.y;
  int t = threadIdx.x;
  __shared__ float tl[64][65];
  int r = t >> 6, c = t & 63;
#pragma unroll
  for (int i = 0; i < 16; ++i) {
    int row = i * 4 + r;
    tl[row][c] = Wo[(size_t)(kt * 64 + row) * D_ + nt * 64 + c];
  }
  __syncthreads();
#pragma unroll
  for (int i = 0; i < 16; ++i) {
    int nrow = i * 4 + r;
    WoT[(size_t)(nt * 64 + nrow) * D_ + kt * 64 + c] = f2bf(tl[c][nrow]);
  }
}

// wave-per-token: theta[:4] -> p -> scores -> softmax addr[8] -> q,k,v rows
__global__ __launch_bounds__(256) void k_qkv(
    const float* __restrict__ query, const float* __restrict__ W_addr,
    const float* __restrict__ b_addr, const float* __restrict__ Hq,
    const float* __restrict__ Hk, const float* __restrict__ Hv,
    const float* __restrict__ bq, const float* __restrict__ bk,
    const float* __restrict__ bv, unsigned short* __restrict__ Qg,
    unsigned short* __restrict__ Kg, unsigned short* __restrict__ Vg) {
  int w = threadIdx.x >> 6, l = threadIdx.x & 63;
  int tk = blockIdx.x * 4 + w;
  int b = tk >> 11, s = tk & (S_ - 1);
  const float* qrow = query + (size_t)tk * D_;
  float th0 = 0.f, th1 = 0.f, th2 = 0.f, th3 = 0.f;
#pragma unroll
  for (int e = 0; e < 4; ++e) {
    float4 qv = *(const float4*)(qrow + l * 16 + e * 4);
    float xs[4] = {qv.x, qv.y, qv.z, qv.w};
#pragma unroll
    for (int kk = 0; kk < 4; ++kk) {
      float4 wr = *(const float4*)(W_addr + (size_t)(l * 16 + e * 4 + kk) * 16);
      th0 += xs[kk] * wr.x;
      th1 += xs[kk] * wr.y;
      th2 += xs[kk] * wr.z;
      th3 += xs[kk] * wr.w;
    }
  }
#pragma unroll
  for (int off = 32; off; off >>= 1) {
    th0 += __shfl_xor(th0, off);
    th1 += __shfl_xor(th1, off);
    th2 += __shfl_xor(th2, off);
    th3 += __shfl_xor(th3, off);
  }
  float thv[4] = {th0 + b_addr[0], th1 + b_addr[1], th2 + b_addr[2],
                  th3 + b_addr[3]};
  float p[4];
#pragma unroll
  for (int q = 0; q < 4; ++q) {
    float sh = __sinf(thv[q] * 0.5f);
    p[q] = thv[q] > 0.f ? sh * sh : 0.f;
  }
  float sc[8];
  float mx = -1e30f;
#pragma unroll
  for (int j = 0; j < 8; ++j) {
    float v = 0.f;
#pragma unroll
    for (int q = 0; q < 4; ++q) v += ((j >> q) & 1) ? p[q] : 1.f - p[q];
    sc[j] = v;
    mx = fmaxf(mx, v);
  }
  float sum = 0.f;
#pragma unroll
  for (int j = 0; j < 8; ++j) {
    sc[j] = __expf(sc[j] - mx);
    sum += sc[j];
  }
  float inv = 1.f / sum;
  float a[8];
#pragma unroll
  for (int j = 0; j < 8; ++j) a[j] = sc[j] * inv;

  const float* Hs[3] = {Hq, Hk, Hv};
  const float* bs[3] = {bq, bk, bv};
  unsigned short* os[3] = {Qg, Kg, Vg};
#pragma unroll
  for (int k = 0; k < 4; ++k) {
    int n0 = k * 256 + l * 4;
    int hh = n0 >> 6, d = n0 & 63;
    size_t obase = ((size_t)(b * H_ + hh) * S_ + s) * HD_ + d;
#pragma unroll
    for (int wi = 0; wi < 3; ++wi) {
      const float* Hh = Hs[wi];
      float4 accv = *(const float4*)(Hh + 8 * D_ + n0);
      float4 bias = *(const float4*)(bs[wi] + n0);
      accv.x += bias.x; accv.y += bias.y; accv.z += bias.z; accv.w += bias.w;
#pragma unroll
      for (int j = 0; j < 8; ++j) {
        float4 hv = *(const float4*)(Hh + j * D_ + n0);
        accv.x += a[j] * hv.x;
        accv.y += a[j] * hv.y;
        accv.z += a[j] * hv.z;
        accv.w += a[j] * hv.w;
      }
      uint2 pk;
      pk.x = (unsigned)f2bf(accv.x) | ((unsigned)f2bf(accv.y) << 16);
      pk.y = (unsigned)f2bf(accv.z) | ((unsigned)f2bf(accv.w) << 16);
      *(uint2*)(os[wi] + obase) = pk;
    }
  }
}

// V (bh,s,d) -> Vt (bh,d,s)
__global__ __launch_bounds__(256) void k_vt(const unsigned short* __restrict__ Vg,
                                            unsigned short* __restrict__ Vtg) {
  int st = blockIdx.x & 31, bh = blockIdx.x >> 5;
  int t = threadIdx.x;
  __shared__ unsigned short tl[64][65];
  int rr = t >> 3, c8 = t & 7;
#pragma unroll
  for (int p = 0; p < 2; ++p) {
    int s = p * 32 + rr;
    uint4 v = *(const uint4*)(Vg + ((size_t)bh * S_ + st * 64 + s) * HD_ + c8 * 8);
    const unsigned short* pv = (const unsigned short*)&v;
#pragma unroll
    for (int j = 0; j < 8; ++j) tl[s][c8 * 8 + j] = pv[j];
  }
  __syncthreads();
#pragma unroll
  for (int p = 0; p < 2; ++p) {
    int d = p * 32 + rr;
    unsigned short o[8];
#pragma unroll
    for (int j = 0; j < 8; ++j) o[j] = tl[c8 * 8 + j][d];
    *(uint4*)(Vtg + ((size_t)bh * HD_ + d) * S_ + st * 64 + c8 * 8) = *(const uint4*)o;
  }
}

// flash attention, swapped-operand 32x32, 8 waves x 32 q (256 q/block),
// double-buffered K/V LDS with reg-staged async split (T14) + setprio (T5).
__global__ __launch_bounds__(512, 4) void k_attn(
    const unsigned short* __restrict__ Qg, const unsigned short* __restrict__ Kg,
    const unsigned short* __restrict__ Vtg, unsigned short* __restrict__ ctxg) {
  int id = blockIdx.x;  // 512 blocks
  // bijective XCD swizzle: each XCD owns 8 heads (K/V footprint = 4MB = L2)
  int xcd = id & 7, kk_ = id >> 3;
  int bh = xcd * 8 + (kk_ >> 3);
  int qt = kk_ & 7;
  int t = threadIdx.x;
  int w = t >> 6, l = t & 63;
  int q31 = l & 31, h = l >> 5;

  __shared__ __align__(16) unsigned short lds[16384];  // 2 x (sK|sVt); reused as sO

  int q0 = qt * 256 + w * 32;
  const unsigned short* qp = Qg + ((size_t)bh * S_ + q0 + q31) * HD_;
  short8 qf0 = *(const short8*)(qp + 0 + h * 8);
  short8 qf1 = *(const short8*)(qp + 16 + h * 8);
  short8 qf2 = *(const short8*)(qp + 32 + h * 8);
  short8 qf3 = *(const short8*)(qp + 48 + h * 8);

  f32x16 accO0 = {}, accO1 = {};
  float m = -1e30f, lsum = 0.f;

  int srow = t >> 3, sc8 = t & 7;  // 64 rows x 8 granules, one uint4 each
  const unsigned short* kgb = Kg + (size_t)bh * S_ * HD_;
  const unsigned short* vtb = Vtg + (size_t)bh * HD_ * S_;
  int di = srow * 64 + ((sc8 * 8) ^ ((srow & 7) << 3));

  // prologue: stage tile 0 into buffer 0
  uint4 rK = *(const uint4*)(kgb + (size_t)srow * HD_ + sc8 * 8);
  uint4 rV = *(const uint4*)(vtb + (size_t)srow * S_ + sc8 * 8);
  *(uint4*)(lds + di) = rK;
  *(uint4*)(lds + 4096 + di) = rV;
  __syncthreads();

  for (int it = 0; it < 32; ++it) {
    int kv0 = it * 64;
    unsigned short* sK = lds + (it & 1) * 8192;
    unsigned short* sVt = sK + 4096;
    if (it < 31) {  // T14: issue next-tile loads early; latency hides under compute
      rK = *(const uint4*)(kgb + (size_t)(kv0 + 64 + srow) * HD_ + sc8 * 8);
      rV = *(const uint4*)(vtb + (size_t)srow * S_ + kv0 + 64 + sc8 * 8);
    }

    // QK^T
    f32x16 accS0 = {}, accS1 = {};
    __builtin_amdgcn_s_setprio(1);
#pragma unroll
    for (int ds = 0; ds < 4; ++ds) {
      short8 qq = ds == 0 ? qf0 : ds == 1 ? qf1 : ds == 2 ? qf2 : qf3;
      {
        int row = q31;
        int g = (ds * 2 + h) ^ (row & 7);
        short8 kf = *(const short8*)(sK + row * 64 + g * 8);
        accS0 = __builtin_amdgcn_mfma_f32_32x32x16_bf16(kf, qq, accS0, 0, 0, 0);
      }
      {
        int row = 32 + q31;
        int g = (ds * 2 + h) ^ (row & 7);
        short8 kf = *(const short8*)(sK + row * 64 + g * 8);
        accS1 = __builtin_amdgcn_mfma_f32_32x32x16_bf16(kf, qq, accS1, 0, 0, 0);
      }
    }
    __builtin_amdgcn_s_setprio(0);

    // in-lane softmax (q = l&31), cross-half via shfl_xor(32)
    float mxv = accS0[0];
#pragma unroll
    for (int r = 1; r < 16; ++r) mxv = fmaxf(mxv, accS0[r]);
#pragma unroll
    for (int r = 0; r < 16; ++r) mxv = fmaxf(mxv, accS1[r]);
    mxv = fmaxf(mxv, __shfl_xor(mxv, 32));
    float pm = mxv * 0.125f;
    if (__ballot(pm > m + 8.f)) {  // defer-max (T13)
      float mn = fmaxf(m, pm);
      float scl = __builtin_exp2f((m - mn) * 1.44269504f);
#pragma unroll
      for (int r = 0; r < 16; ++r) {
        accO0[r] *= scl;
        accO1[r] *= scl;
      }
      lsum *= scl;
      m = mn;
    }
    const float K1 = 0.125f * 1.44269504f;
    float m2 = m * 1.44269504f;
    float ts = 0.f;
#pragma unroll
    for (int r = 0; r < 16; ++r) {
      float p0 = __builtin_exp2f(accS0[r] * K1 - m2);
      float p1 = __builtin_exp2f(accS1[r] * K1 - m2);
      accS0[r] = p0;
      accS1[r] = p1;
      ts += p0 + p1;
    }
    ts += __shfl_xor(ts, 32);
    lsum += ts;

    // P -> bf16 B-fragments (cvt_pk + half-exchange)
    short8 pb[4];
#pragma unroll
    for (int ks = 0; ks < 4; ++ks) {
      const int r0 = 8 * (ks & 1);
      float v0, v1, v2, v3, v4, v5, v6, v7;
      if (ks < 2) {
        v0 = accS0[r0 + 0]; v1 = accS0[r0 + 1]; v2 = accS0[r0 + 2]; v3 = accS0[r0 + 3];
        v4 = accS0[r0 + 4]; v5 = accS0[r0 + 5]; v6 = accS0[r0 + 6]; v7 = accS0[r0 + 7];
      } else {
        v0 = accS1[r0 + 0]; v1 = accS1[r0 + 1]; v2 = accS1[r0 + 2]; v3 = accS1[r0 + 3];
        v4 = accS1[r0 + 4]; v5 = accS1[r0 + 5]; v6 = accS1[r0 + 6]; v7 = accS1[r0 + 7];
      }
      unsigned X0 = cvtpk(v0, v1), X1 = cvtpk(v2, v3);
      unsigned Y0 = cvtpk(v4, v5), Y1 = cvtpk(v6, v7);
      unsigned tX0 = __shfl_xor(X0, 32), tX1 = __shfl_xor(X1, 32);
      unsigned tY0 = __shfl_xor(Y0, 32), tY1 = __shfl_xor(Y1, 32);
      union { unsigned u[4]; short8 s8; } uu;
      uu.u[0] = h ? tY0 : X0;
      uu.u[1] = h ? tY1 : X1;
      uu.u[2] = h ? Y0 : tX0;
      uu.u[3] = h ? Y1 : tX1;
      pb[ks] = uu.s8;
    }

    // PV
    __builtin_amdgcn_s_setprio(1);
    {
      int row = q31;
      int rs = row & 7;
#pragma unroll
      for (int ks = 0; ks < 4; ++ks) {
        int g = (ks * 2 + h) ^ rs;
        short8 vf = *(const short8*)(sVt + row * 64 + g * 8);
        accO0 = __builtin_amdgcn_mfma_f32_32x32x16_bf16(vf, pb[ks], accO0, 0, 0, 0);
      }
    }
    {
      int row = 32 + q31;
      int rs = row & 7;
#pragma unroll
      for (int ks = 0; ks < 4; ++ks) {
        int g = (ks * 2 + h) ^ rs;
        short8 vf = *(const short8*)(sVt + row * 64 + g * 8);
        accO1 = __builtin_amdgcn_mfma_f32_32x32x16_bf16(vf, pb[ks], accO1, 0, 0, 0);
      }
    }
    __builtin_amdgcn_s_setprio(0);

    if (it < 31) {  // T14: write next tile to the other buffer
      unsigned short* dK = lds + ((it + 1) & 1) * 8192;
      *(uint4*)(dK + di) = rK;
      *(uint4*)(dK + 4096 + di) = rV;
    }
    __syncthreads();
  }

  // O out: normalize, bounce through LDS for coalesced stores
  float inv = 1.f / lsum;
  unsigned short* sO = lds + w * 2048;  // [32 q][64 d], granule-8 XOR swizzle
#pragma unroll
  for (int r = 0; r < 16; ++r) {
    int dl = (r & 3) + 8 * (r >> 2) + 4 * h;
    int swz = (q31 & 7) << 3;
    sO[q31 * 64 + (dl ^ swz)] = f2bf(accO0[r] * inv);
    sO[q31 * 64 + ((32 + dl) ^ swz)] = f2bf(accO1[r] * inv);
  }
  __syncthreads();
  int b = bh >> 4, head = bh & 15;
  int rr = l & 31, hh = l >> 5;
  unsigned short* orow = ctxg + ((size_t)(b * S_ + q0 + rr)) * D_ + head * HD_;
#pragma unroll
  for (int j = 0; j < 4; ++j) {
    int g = hh * 4 + j;
    uint4 vv = *(const uint4*)(sO + rr * 64 + ((g ^ (rr & 7)) * 8));
    *(uint4*)(orow + g * 8) = vv;
  }
}

// out[8192,1024] = ctx @ Wo + bo
__global__ __launch_bounds__(256) void k_out(const unsigned short* __restrict__ Ag,
                                             const unsigned short* __restrict__ Btg,
                                             const float* __restrict__ bo,
                                             float* __restrict__ out) {
  int mt = blockIdx.x;
  int nt = blockIdx.y;
  int t = threadIdx.x;
  int w = t >> 6, l = t & 63;
  int l15 = l & 15, l4 = l >> 4;
  int wr = w >> 1, wc = w & 1;
  __shared__ __align__(16) unsigned short sA[128 * 64];
  __shared__ __align__(16) unsigned short sB[128 * 64];
  f32x4 acc[4][4];
#pragma unroll
  for (int mm = 0; mm < 4; ++mm)
#pragma unroll
    for (int nn = 0; nn < 4; ++nn) acc[mm][nn] = (f32x4){0.f, 0.f, 0.f, 0.f};
  int srow = t >> 3, sc8 = t & 7;
  for (int kt = 0; kt < 16; ++kt) {
    int k0 = kt * 64;
    __syncthreads();
#pragma unroll
    for (int p = 0; p < 4; ++p) {
      int row = p * 32 + srow;
      int di = row * 64 + ((sc8 * 8) ^ ((row & 7) << 3));
      *(uint4*)(sA + di) =
          *(const uint4*)(Ag + (size_t)(mt * 128 + row) * D_ + k0 + sc8 * 8);
      *(uint4*)(sB + di) =
          *(const uint4*)(Btg + (size_t)(nt * 128 + row) * D_ + k0 + sc8 * 8);
    }
    __syncthreads();
    short8 a[4][2];
#pragma unroll
    for (int mm = 0; mm < 4; ++mm) {
      int row = wr * 64 + mm * 16 + l15;
      int sw = (row & 7) << 3;
      a[mm][0] = *(const short8*)(sA + row * 64 + ((l4 * 8) ^ sw));
      a[mm][1] = *(const short8*)(sA + row * 64 + ((32 + l4 * 8) ^ sw));
    }
#pragma unroll
    for (int nn = 0; nn < 4; ++nn) {
      int row = wc * 64 + nn * 16 + l15;
      int sw = (row & 7) << 3;
      short8 b0 = *(const short8*)(sB + row * 64 + ((l4 * 8) ^ sw));
      short8 b1 = *(const short8*)(sB + row * 64 + ((32 + l4 * 8) ^ sw));
#pragma unroll
      for (int mm = 0; mm < 4; ++mm) {
        acc[mm][nn] = __builtin_amdgcn_mfma_f32_16x16x32_bf16(a[mm][0], b0, acc[mm][nn], 0, 0, 0);
        acc[mm][nn] = __builtin_amdgcn_mfma_f32_16x16x32_bf16(a[mm][1], b1, acc[mm][nn], 0, 0, 0);
      }
    }
  }
#pragma unroll
  for (int mm = 0; mm < 4; ++mm) {
#pragma unroll
    for (int r = 0; r < 4; ++r) {
      int mrow = mt * 128 + wr * 64 + mm * 16 + l4 * 4 + r;
      float* orow = out + (size_t)mrow * D_ + nt * 128 + wc * 64;
#pragma unroll
      for (int nn = 0; nn < 4; ++nn) {
        int n = nn * 16 + l15;
        orow[n] = acc[mm][nn][r] + bo[nt * 128 + wc * 64 + n];
      }
    }
  }
}

extern "C" void kernel_launch(void* const* d_in, const int* in_sizes, int n_in,
                              void* d_out, int out_size, void* d_ws, size_t ws_size,
                              hipStream_t stream) {
  const float* query = (const float*)d_in[0];
  const float* W_addr = (const float*)d_in[1];
  const float* b_addr = (const float*)d_in[2];
  const float* memory = (const float*)d_in[3];
  const float* W_out = (const float*)d_in[4];
  const float* b_out = (const float*)d_in[5];
  const float* Wq = (const float*)d_in[6];
  const float* bq = (const float*)d_in[7];
  const float* Wk = (const float*)d_in[8];
  const float* bk = (const float*)d_in[9];
  const float* Wv = (const float*)d_in[10];
  const float* bv = (const float*)d_in[11];
  const float* Wo = (const float*)d_in[12];
  const float* bo = (const float*)d_in[13];
  float* out = (float*)d_out;

  char* ws = (char*)d_ws;
  size_t off = 0;
  auto alloc = [&](size_t bytes) {
    char* p = ws + off;
    off = (off + bytes + 255) & ~(size_t)255;
    return p;
  };
  float* G = (float*)alloc(9 * D_ * sizeof(float));
  float* HqA = (float*)alloc(9 * D_ * sizeof(float));
  float* HkA = (float*)alloc(9 * D_ * sizeof(float));
  float* HvA = (float*)alloc(9 * D_ * sizeof(float));
  float* partmw = (float*)alloc(16 * J_ * D_ * sizeof(float));
  float* partq = (float*)alloc(3 * 4 * 9 * D_ * sizeof(float));
  unsigned short* WoT = (unsigned short*)alloc((size_t)D_ * D_ * 2);
  unsigned short* Vg = (unsigned short*)alloc((size_t)BH_ * S_ * HD_ * 2);
  unsigned short* Vtg = (unsigned short*)alloc((size_t)BH_ * S_ * HD_ * 2);
  unsigned short* Qg = (unsigned short*)d_out;
  unsigned short* Kg = Qg + (size_t)BH_ * S_ * HD_;
  unsigned short* ctx = Vg;

  k_mw_part<<<256, 256, 0, stream>>>(memory, W_out, partmw);
  k_mw_red<<<36, 256, 0, stream>>>(partmw, b_out, G);
  k_mwq_part<<<192, 256, 0, stream>>>(G, Wq, Wk, Wv, partq);
  k_mwq_red<<<108, 256, 0, stream>>>(partq, HqA, HkA, HvA);
  k_wot<<<dim3(16, 16), 256, 0, stream>>>(Wo, WoT);
  k_qkv<<<B_ * S_ / 4, 256, 0, stream>>>(query, W_addr, b_addr, HqA, HkA, HvA,
                                         bq, bk, bv, Qg, Kg, Vg);
  k_vt<<<BH_ * 32, 256, 0, stream>>>(Vg, Vtg);
  k_attn<<<512, 512, 0, stream>>>(Qg, Kg, Vtg, ctx);
  k_out<<<dim3(64, 8), 256, 0, stream>>>(ctx, WoT, bo, out);
}